// Round 22
// baseline (71.044 us; speedup 1.0000x reference)
//
#include <hip/hip_runtime.h>
#include <hip/hip_bf16.h>
#include <stdint.h>

#define NB 2
#define SEQ 4096
#define HID 256
#define NHEAD 8
#define NKVH 4
#define HDIM 32

typedef __bf16 bf16;
typedef __bf16 bf16x8 __attribute__((ext_vector_type(8)));
typedef float f32x4 __attribute__((ext_vector_type(4)));

static __device__ __forceinline__ uint16_t bfbits(float f) {
    bf16 h = (bf16)f;
    return __builtin_bit_cast(uint16_t, h);
}
static __device__ __forceinline__ uint32_t pack_bf16(float lo, float hi) {
    return (uint32_t)bfbits(lo) | ((uint32_t)bfbits(hi) << 16);
}
// raw v_exp_f32: no libm range wrapper.  exp2(-1e30) == +0 in HW.
static __device__ __forceinline__ float fexp2(float x) {
#if __has_builtin(__builtin_amdgcn_exp2f)
    return __builtin_amdgcn_exp2f(x);
#else
    float r; asm("v_exp_f32 %0, %1" : "=v"(r) : "v"(x)); return r;
#endif
}
// async global->LDS DMA, 16B per lane.
static __device__ __forceinline__ void gld_lds16(const void* g, void* l) {
    __builtin_amdgcn_global_load_lds(
        (const __attribute__((address_space(1))) void*)g,
        (__attribute__((address_space(3))) void*)l, 16, 0, 0);
}

// ---------------------------------------------------------------------------
// Kernel 1: QKV projection + RoPE (proven R16 version, f32 inputs).
// ---------------------------------------------------------------------------
__global__ __launch_bounds__(256) void qkv_proj(
    const float* __restrict__ hs, const float* __restrict__ Wq,
    const float* __restrict__ Wk, const float* __restrict__ Wv,
    bf16* __restrict__ qws, bf16* __restrict__ kws, bf16* __restrict__ vtws)
{
    __shared__ bf16 As[64][136];
    __shared__ bf16 Bs[64][136];
    const int t = threadIdx.x;
    const int wid = t >> 6, lane = t & 63;
    const int g = lane >> 4, c = lane & 15;
    const int n0 = blockIdx.x * 64;
    const int m0 = blockIdx.y * 64;

    const float* bsrc; int ro;
    if (n0 < 256)      { bsrc = Wq; ro = n0; }
    else if (n0 < 384) { bsrc = Wk; ro = n0 - 256; }
    else               { bsrc = Wv; ro = n0 - 384; }

    const f32x4 zf = {0.f, 0.f, 0.f, 0.f};
    f32x4 acc[4] = {zf, zf, zf, zf};

    const int c4 = t & 31;
    const int rb = t >> 5;

    for (int ks = 0; ks < 256; ks += 128) {
        __syncthreads();
        #pragma unroll
        for (int i = 0; i < 8; ++i) {
            int row = i * 8 + rb;
            float4 v = *(const float4*)&hs[(size_t)(m0 + row) * HID + ks + c4 * 4];
            ushort4 w; w.x = bfbits(v.x); w.y = bfbits(v.y); w.z = bfbits(v.z); w.w = bfbits(v.w);
            *(ushort4*)&As[row][c4 * 4] = w;
        }
        #pragma unroll
        for (int i = 0; i < 8; ++i) {
            int row = i * 8 + rb;
            float4 v = *(const float4*)&bsrc[(size_t)(ro + row) * HID + ks + c4 * 4];
            ushort4 w; w.x = bfbits(v.x); w.y = bfbits(v.y); w.z = bfbits(v.z); w.w = bfbits(v.w);
            *(ushort4*)&Bs[row][c4 * 4] = w;
        }
        __syncthreads();
        #pragma unroll
        for (int kk = 0; kk < 128; kk += 32) {
            bf16x8 af = *(const bf16x8*)&As[wid * 16 + c][kk + g * 8];
            #pragma unroll
            for (int nt = 0; nt < 4; ++nt) {
                bf16x8 bfr = *(const bf16x8*)&Bs[nt * 16 + c][kk + g * 8];
                acc[nt] = __builtin_amdgcn_mfma_f32_16x16x32_bf16(af, bfr, acc[nt], 0, 0, 0);
            }
        }
    }

    const float qscale = 1.4426950408889634f * 0.17677669529663687f; // log2e/sqrt(32)
    const float invf = exp2f(-0.83048202372184f * (float)c);          // 10000^(-c/16)
    #pragma unroll
    for (int r = 0; r < 4; ++r) {
        int m = m0 + wid * 16 + g * 4 + r;
        int b = m >> 12, s = m & (SEQ - 1);
        float sn, cs;
        sincosf((float)s * invf, &sn, &cs);
        if (n0 < 256) {
            #pragma unroll
            for (int np = 0; np < 4; np += 2) {
                int h = (n0 + np * 16) >> 5;
                float x1 = acc[np][r], x2 = acc[np + 1][r];
                float y1 = (x1 * cs - x2 * sn) * qscale;
                float y2 = (x2 * cs + x1 * sn) * qscale;
                size_t base = ((size_t)(b * NHEAD + h) * SEQ + s) * HDIM;
                qws[base + c] = (bf16)y1;
                qws[base + 16 + c] = (bf16)y2;
            }
        } else if (n0 < 384) {
            #pragma unroll
            for (int np = 0; np < 4; np += 2) {
                int kh = (n0 - 256 + np * 16) >> 5;
                float x1 = acc[np][r], x2 = acc[np + 1][r];
                float y1 = x1 * cs - x2 * sn;
                float y2 = x2 * cs + x1 * sn;
                size_t base = ((size_t)(b * NKVH + kh) * SEQ + s) * HDIM;
                kws[base + c] = (bf16)y1;
                kws[base + 16 + c] = (bf16)y2;
            }
        } else {
            #pragma unroll
            for (int nt = 0; nt < 4; ++nt) {
                int ng = n0 + nt * 16 + c - 384;
                int vh = ng >> 5, d = ng & 31;
                vtws[((size_t)(b * NKVH + vh) * HDIM + d) * SEQ + s] = (bf16)acc[nt][r];
            }
        }
    }
}

// ---------------------------------------------------------------------------
// Kernel 2: causal flash attention (R20 verbatim): 2-way cross-block K-split,
// ring-4 LDS (two 64-key chunks per barrier), async global_load_lds.
// ---------------------------------------------------------------------------
#define ATT_CHUNK(CI, KBUF, VBUF)                                              \
  do {                                                                         \
    const char* kbuf = (KBUF);                                                 \
    const char* vbuf = (VBUF);                                                 \
    bf16x8 kf0 = *(const bf16x8*)(kbuf + kro);                                 \
    bf16x8 kf1 = *(const bf16x8*)(kbuf + kro + 256);                           \
    bf16x8 kf2 = *(const bf16x8*)(kbuf + kro + 2048);                          \
    bf16x8 kf3 = *(const bf16x8*)(kbuf + kro + 2304);                          \
    bf16x8 vf00 = *(const bf16x8*)(vbuf + vro0 + ((g ^ cx) << 4));             \
    bf16x8 vf01 = *(const bf16x8*)(vbuf + vro1 + ((g ^ cx) << 4));             \
    bf16x8 vf10 = *(const bf16x8*)(vbuf + vro0 + (((4 + g) ^ cx) << 4));       \
    bf16x8 vf11 = *(const bf16x8*)(vbuf + vro1 + (((4 + g) ^ cx) << 4));       \
    const bool diag = ((CI) == d_w);                                           \
    const int qbase = (w & 1) * 32 + c;                                        \
    {                                                                          \
        f32x4 st0 = __builtin_amdgcn_mfma_f32_16x16x32_bf16(kf0, qf0, zf, 0, 0, 0); \
        f32x4 st1 = __builtin_amdgcn_mfma_f32_16x16x32_bf16(kf1, qf0, zf, 0, 0, 0); \
        f32x4 st2 = __builtin_amdgcn_mfma_f32_16x16x32_bf16(kf2, qf0, zf, 0, 0, 0); \
        f32x4 st3 = __builtin_amdgcn_mfma_f32_16x16x32_bf16(kf3, qf0, zf, 0, 0, 0); \
        if (diag) {                                                            \
            const int qoff = qbase;                                            \
            _Pragma("unroll")                                                  \
            for (int rr = 0; rr < 4; ++rr) {                                   \
                if (8 * g + rr > qoff)          st0[rr] = -1e30f;              \
                if (8 * g + 4 + rr > qoff)      st1[rr] = -1e30f;              \
                if (32 + 8 * g + rr > qoff)     st2[rr] = -1e30f;              \
                if (32 + 8 * g + 4 + rr > qoff) st3[rr] = -1e30f;              \
            }                                                                  \
        }                                                                      \
        float p00 = fexp2(st0[0]), p01 = fexp2(st0[1]), p02 = fexp2(st0[2]), p03 = fexp2(st0[3]); \
        float p10 = fexp2(st1[0]), p11 = fexp2(st1[1]), p12 = fexp2(st1[2]), p13 = fexp2(st1[3]); \
        float p20 = fexp2(st2[0]), p21 = fexp2(st2[1]), p22 = fexp2(st2[2]), p23 = fexp2(st2[3]); \
        float p30 = fexp2(st3[0]), p31 = fexp2(st3[1]), p32 = fexp2(st3[2]), p33 = fexp2(st3[3]); \
        union { uint32_t u[4]; bf16x8 v; } pb0, pb1;                           \
        asm("v_cvt_pk_bf16_f32 %0, %1, %2" : "=v"(pb0.u[0]) : "v"(p00), "v"(p01)); \
        asm("v_cvt_pk_bf16_f32 %0, %1, %2" : "=v"(pb0.u[1]) : "v"(p02), "v"(p03)); \
        asm("v_cvt_pk_bf16_f32 %0, %1, %2" : "=v"(pb0.u[2]) : "v"(p10), "v"(p11)); \
        asm("v_cvt_pk_bf16_f32 %0, %1, %2" : "=v"(pb0.u[3]) : "v"(p12), "v"(p13)); \
        asm("v_cvt_pk_bf16_f32 %0, %1, %2" : "=v"(pb1.u[0]) : "v"(p20), "v"(p21)); \
        asm("v_cvt_pk_bf16_f32 %0, %1, %2" : "=v"(pb1.u[1]) : "v"(p22), "v"(p23)); \
        asm("v_cvt_pk_bf16_f32 %0, %1, %2" : "=v"(pb1.u[2]) : "v"(p30), "v"(p31)); \
        asm("v_cvt_pk_bf16_f32 %0, %1, %2" : "=v"(pb1.u[3]) : "v"(p32), "v"(p33)); \
        o00 = __builtin_amdgcn_mfma_f32_16x16x32_bf16(vf00, pb0.v, o00, 0, 0, 0); \
        o01 = __builtin_amdgcn_mfma_f32_16x16x32_bf16(vf01, pb0.v, o01, 0, 0, 0); \
        ol0 = __builtin_amdgcn_mfma_f32_16x16x32_bf16(onesf.v, pb0.v, ol0, 0, 0, 0); \
        o00 = __builtin_amdgcn_mfma_f32_16x16x32_bf16(vf10, pb1.v, o00, 0, 0, 0); \
        o01 = __builtin_amdgcn_mfma_f32_16x16x32_bf16(vf11, pb1.v, o01, 0, 0, 0); \
        ol0 = __builtin_amdgcn_mfma_f32_16x16x32_bf16(onesf.v, pb1.v, ol0, 0, 0, 0); \
    }                                                                          \
    {                                                                          \
        f32x4 st0 = __builtin_amdgcn_mfma_f32_16x16x32_bf16(kf0, qf1, zf, 0, 0, 0); \
        f32x4 st1 = __builtin_amdgcn_mfma_f32_16x16x32_bf16(kf1, qf1, zf, 0, 0, 0); \
        f32x4 st2 = __builtin_amdgcn_mfma_f32_16x16x32_bf16(kf2, qf1, zf, 0, 0, 0); \
        f32x4 st3 = __builtin_amdgcn_mfma_f32_16x16x32_bf16(kf3, qf1, zf, 0, 0, 0); \
        if (diag) {                                                            \
            const int qoff = qbase + 16;                                       \
            _Pragma("unroll")                                                  \
            for (int rr = 0; rr < 4; ++rr) {                                   \
                if (8 * g + rr > qoff)          st0[rr] = -1e30f;              \
                if (8 * g + 4 + rr > qoff)      st1[rr] = -1e30f;              \
                if (32 + 8 * g + rr > qoff)     st2[rr] = -1e30f;              \
                if (32 + 8 * g + 4 + rr > qoff) st3[rr] = -1e30f;              \
            }                                                                  \
        }                                                                      \
        float p00 = fexp2(st0[0]), p01 = fexp2(st0[1]), p02 = fexp2(st0[2]), p03 = fexp2(st0[3]); \
        float p10 = fexp2(st1[0]), p11 = fexp2(st1[1]), p12 = fexp2(st1[2]), p13 = fexp2(st1[3]); \
        float p20 = fexp2(st2[0]), p21 = fexp2(st2[1]), p22 = fexp2(st2[2]), p23 = fexp2(st2[3]); \
        float p30 = fexp2(st3[0]), p31 = fexp2(st3[1]), p32 = fexp2(st3[2]), p33 = fexp2(st3[3]); \
        union { uint32_t u[4]; bf16x8 v; } pb0, pb1;                           \
        asm("v_cvt_pk_bf16_f32 %0, %1, %2" : "=v"(pb0.u[0]) : "v"(p00), "v"(p01)); \
        asm("v_cvt_pk_bf16_f32 %0, %1, %2" : "=v"(pb0.u[1]) : "v"(p02), "v"(p03)); \
        asm("v_cvt_pk_bf16_f32 %0, %1, %2" : "=v"(pb0.u[2]) : "v"(p10), "v"(p11)); \
        asm("v_cvt_pk_bf16_f32 %0, %1, %2" : "=v"(pb0.u[3]) : "v"(p12), "v"(p13)); \
        asm("v_cvt_pk_bf16_f32 %0, %1, %2" : "=v"(pb1.u[0]) : "v"(p20), "v"(p21)); \
        asm("v_cvt_pk_bf16_f32 %0, %1, %2" : "=v"(pb1.u[1]) : "v"(p22), "v"(p23)); \
        asm("v_cvt_pk_bf16_f32 %0, %1, %2" : "=v"(pb1.u[2]) : "v"(p30), "v"(p31)); \
        asm("v_cvt_pk_bf16_f32 %0, %1, %2" : "=v"(pb1.u[3]) : "v"(p32), "v"(p33)); \
        o10 = __builtin_amdgcn_mfma_f32_16x16x32_bf16(vf00, pb0.v, o10, 0, 0, 0); \
        o11 = __builtin_amdgcn_mfma_f32_16x16x32_bf16(vf01, pb0.v, o11, 0, 0, 0); \
        ol1 = __builtin_amdgcn_mfma_f32_16x16x32_bf16(onesf.v, pb0.v, ol1, 0, 0, 0); \
        o10 = __builtin_amdgcn_mfma_f32_16x16x32_bf16(vf10, pb1.v, o10, 0, 0, 0); \
        o11 = __builtin_amdgcn_mfma_f32_16x16x32_bf16(vf11, pb1.v, o11, 0, 0, 0); \
        ol1 = __builtin_amdgcn_mfma_f32_16x16x32_bf16(onesf.v, pb1.v, ol1, 0, 0, 0); \
    }                                                                          \
  } while (0)

__global__ __launch_bounds__(256, 4) void attn_fwd(
    const bf16* __restrict__ qws, const bf16* __restrict__ kws,
    const bf16* __restrict__ vtws,
    float* __restrict__ Oa, float* __restrict__ Ob,
    float* __restrict__ la, float* __restrict__ lb)
{
    __shared__ char smem[32768];        // K ring 4x4KB @0, V ring 4x4KB @16384
    const int t = threadIdx.x;
    const int w = t >> 6, lane = t & 63;
    const int g = lane >> 4, c = lane & 15;
    const int wg = blockIdx.x;
    const int h = wg & 7;                    // XCD pin
    const int rest = wg >> 3;                // 0..127
    const int half = rest & 1;
    const int r2 = rest >> 1;                // 0..63
    const int b = r2 & 1;
    const int T = 31 - (r2 >> 1);            // descending: longest first
    const int kvh = h >> 1;
    const bf16* Kg = kws + (size_t)(b * NKVH + kvh) * SEQ * HDIM;
    const bf16* Vg = vtws + (size_t)(b * NKVH + kvh) * HDIM * SEQ;
    const int cbase = half * (T + 1);        // first chunk
    const int nloc = T + 1;                  // chunks this block
    const int q0 = T * 128 + w * 32;         // wave's first query
    const int d_w = 2 * T + (w >> 1);        // wave's diagonal chunk (global)

    const bf16* Qb = qws + (size_t)(b * NHEAD + h) * SEQ * HDIM;
    bf16x8 qf0 = *(const bf16x8*)&Qb[(size_t)(q0 + c) * HDIM + g * 8];
    bf16x8 qf1 = *(const bf16x8*)&Qb[(size_t)(q0 + 16 + c) * HDIM + g * 8];

    const int sd = t >> 3, sseg = t & 7;
    const bf16* kg_t = Kg + t * 8;                                    // + ch*2048
    const bf16* vg_t = Vg + (size_t)sd * SEQ + (sseg ^ (sd & 7)) * 8; // + ch*64
    char* kl = smem + w * 1024;              // + slot*4096
    char* vl = smem + 16384 + w * 1024;      // + slot*4096

    const int kperm = 8 * (c >> 2) + (c & 3);
    const int kro = kperm * 64 + g * 16;
    const int cx = c & 7;
    const int vro0 = c * 128, vro1 = (16 + c) * 128;

    const f32x4 zf = {0.f, 0.f, 0.f, 0.f};
    union { uint32_t u[4]; bf16x8 v; } onesf;
    onesf.u[0] = onesf.u[1] = onesf.u[2] = onesf.u[3] = 0x3F803F80u;

    f32x4 o00 = zf, o01 = zf, ol0 = zf;
    f32x4 o10 = zf, o11 = zf, ol1 = zf;

    // prologue: stage chunks 0 and 1 into slots 0,1
    gld_lds16(kg_t + (size_t)cbase * 2048, kl);
    gld_lds16(vg_t + (size_t)cbase * 64, vl);
    if (1 < nloc) {
        gld_lds16(kg_t + (size_t)(cbase + 1) * 2048, kl + 4096);
        gld_lds16(vg_t + (size_t)(cbase + 1) * 64, vl + 4096);
    }
    __syncthreads();

    const int nit = (nloc + 1) >> 1;
    #pragma unroll 1
    for (int it = 0; it < nit; ++it) {
        const int s0 = 2 * it, s1 = s0 + 1;
        if (s0 + 2 < nloc) {
            gld_lds16(kg_t + (size_t)(cbase + s0 + 2) * 2048, kl + ((s0 + 2) & 3) * 4096);
            gld_lds16(vg_t + (size_t)(cbase + s0 + 2) * 64, vl + ((s0 + 2) & 3) * 4096);
        }
        if (s1 + 2 < nloc) {
            gld_lds16(kg_t + (size_t)(cbase + s1 + 2) * 2048, kl + ((s1 + 2) & 3) * 4096);
            gld_lds16(vg_t + (size_t)(cbase + s1 + 2) * 64, vl + ((s1 + 2) & 3) * 4096);
        }
        const int ci0 = cbase + s0;
        if (ci0 <= d_w) {
            ATT_CHUNK(ci0, smem + (s0 & 3) * 4096 + 0,
                           smem + 16384 + (s0 & 3) * 4096);
        }
        const int ci1 = cbase + s1;
        if (s1 < nloc && ci1 <= d_w) {
            ATT_CHUNK(ci1, smem + (s1 & 3) * 4096 + 0,
                           smem + 16384 + (s1 & 3) * 4096);
        }
        __syncthreads();
    }

    // epilogue: un-normalized f32 partials; tr overlays dead K region
    float* tr = (float*)(smem + w * 2112);
    float* Op = half ? Ob : Oa;
    float* lp = half ? lb : la;
    #pragma unroll 1
    for (int j = 0; j < 2; ++j) {
        f32x4 a0 = j ? o10 : o00;
        f32x4 a1 = j ? o11 : o01;
        f32x4 al = j ? ol1 : ol0;
        #pragma unroll
        for (int rr = 0; rr < 4; ++rr) {
            tr[c * 33 + 4 * g + rr]      = a0[rr];
            tr[c * 33 + 16 + 4 * g + rr] = a1[rr];
        }
        if (g == 0) lp[((size_t)b * SEQ + q0 + j * 16 + c) * 8 + h] = al[0];
        int q = lane >> 2, dp = (lane & 3) * 8;
        size_t m = (size_t)b * SEQ + q0 + j * 16 + q;
        float4 f0 = make_float4(tr[q * 33 + dp + 0], tr[q * 33 + dp + 1],
                                tr[q * 33 + dp + 2], tr[q * 33 + dp + 3]);
        float4 f1 = make_float4(tr[q * 33 + dp + 4], tr[q * 33 + dp + 5],
                                tr[q * 33 + dp + 6], tr[q * 33 + dp + 7]);
        *(float4*)&Op[m * HID + h * HDIM + dp]     = f0;
        *(float4*)&Op[m * HID + h * HDIM + dp + 4] = f1;
    }
}

// ---------------------------------------------------------------------------
// Kernel 3: FUSED combine + output projection, TWO-PASS K loop (fixed R21
// layout bug: [64][136]/[128][136] tiles hold 128-col chunks, staged per
// pass; acc persists across passes).  Grid (2 n-halves, 128 m-tiles).
// ---------------------------------------------------------------------------
__global__ __launch_bounds__(256, 2) void outp3(
    const float* __restrict__ Oa, const float* __restrict__ Ob,
    const float* __restrict__ la, const float* __restrict__ lb,
    const float* __restrict__ Wo, float* __restrict__ out)
{
    __shared__ bf16 As[64][136];
    __shared__ bf16 Bs[128][136];
    const int t = threadIdx.x;
    const int wid = t >> 6, lane = t & 63;
    const int g = lane >> 4, c = lane & 15;
    const int n0 = blockIdx.x * 128;
    const int m0 = blockIdx.y * 64;

    const int c4 = t & 31;           // float4 column within 128-chunk
    const int rb = t >> 5;           // 0..7

    const f32x4 zf = {0.f, 0.f, 0.f, 0.f};
    f32x4 acc[8] = {zf, zf, zf, zf, zf, zf, zf, zf};

    for (int ks = 0; ks < 256; ks += 128) {
        __syncthreads();
        const int col = ks + c4 * 4;
        const int hh = col >> 5;
        // A: combine (Oa+Ob)/(la+lb) -> bf16, 64 rows x 128 cols per pass
        #pragma unroll
        for (int i = 0; i < 8; ++i) {
            const int row = i * 8 + rb;
            const size_t m = (size_t)(m0 + row);
            const float inv = 1.0f / (la[m * 8 + hh] + lb[m * 8 + hh]);
            float4 a = *(const float4*)&Oa[m * HID + col];
            float4 b = *(const float4*)&Ob[m * HID + col];
            ushort4 w;
            w.x = bfbits((a.x + b.x) * inv);
            w.y = bfbits((a.y + b.y) * inv);
            w.z = bfbits((a.z + b.z) * inv);
            w.w = bfbits((a.w + b.w) * inv);
            *(ushort4*)&As[row][c4 * 4] = w;
        }
        // B: convert Wo n-half, 128 rows x 128 cols per pass
        #pragma unroll
        for (int i = 0; i < 16; ++i) {
            const int row = i * 8 + rb;
            float4 v = *(const float4*)&Wo[(size_t)(n0 + row) * HID + col];
            ushort4 w; w.x = bfbits(v.x); w.y = bfbits(v.y); w.z = bfbits(v.z); w.w = bfbits(v.w);
            *(ushort4*)&Bs[row][c4 * 4] = w;
        }
        __syncthreads();
        #pragma unroll
        for (int kk = 0; kk < 128; kk += 32) {
            bf16x8 af = *(const bf16x8*)&As[wid * 16 + c][kk + g * 8];
            #pragma unroll
            for (int nt = 0; nt < 8; ++nt) {
                bf16x8 bfr = *(const bf16x8*)&Bs[nt * 16 + c][kk + g * 8];
                acc[nt] = __builtin_amdgcn_mfma_f32_16x16x32_bf16(af, bfr, acc[nt], 0, 0, 0);
            }
        }
    }

    #pragma unroll
    for (int nt = 0; nt < 8; ++nt) {
        #pragma unroll
        for (int rr = 0; rr < 4; ++rr) {
            int m = m0 + wid * 16 + g * 4 + rr;
            out[(size_t)m * HID + n0 + nt * 16 + c] = acc[nt][rr];
        }
    }
}

extern "C" void kernel_launch(void* const* d_in, const int* in_sizes, int n_in,
                              void* d_out, int out_size, void* d_ws, size_t ws_size,
                              hipStream_t stream) {
    const float* hs = (const float*)d_in[0];
    const float* Wq = (const float*)d_in[1];
    const float* Wk = (const float*)d_in[2];
    const float* Wv = (const float*)d_in[3];
    const float* Wo = (const float*)d_in[4];
    char* ws = (char*)d_ws;
    bf16* qws  = (bf16*)(ws);                 // [2][8][4096][32]   4,194,304 B
    bf16* kws  = (bf16*)(ws + 4194304);       // [2][4][4096][32]   2,097,152 B
    bf16* vtws = (bf16*)(ws + 6291456);       // [2][4][32][4096]   2,097,152 B
    float* Oa  = (float*)(ws + 8388608);      // [8192][256] f32    8,388,608 B
    float* Ob  = (float*)(ws + 16777216);     // [8192][256] f32    8,388,608 B
    float* la  = (float*)(ws + 25165824);     // [8192][8]  f32       262,144 B
    float* lb  = (float*)(ws + 25427968);     // [8192][8]  f32       262,144 B

    qkv_proj<<<dim3(8, 128), 256, 0, stream>>>(hs, Wq, Wk, Wv, qws, kws, vtws);
    attn_fwd<<<1024, 256, 0, stream>>>(qws, kws, vtws, Oa, Ob, la, lb);
    outp3<<<dim3(2, 128), 256, 0, stream>>>(Oa, Ob, la, lb, Wo, (float*)d_out);
}

// Round 23
// 62.255 us; speedup vs baseline: 1.1412x; 1.1412x over previous
//
#include <hip/hip_runtime.h>
#include <hip/hip_bf16.h>
#include <stdint.h>

#define NB 2
#define SEQ 4096
#define HID 256
#define NHEAD 8
#define NKVH 4
#define HDIM 32

typedef __bf16 bf16;
typedef __bf16 bf16x8 __attribute__((ext_vector_type(8)));
typedef float f32x4 __attribute__((ext_vector_type(4)));

static __device__ __forceinline__ uint16_t bfbits(float f) {
    bf16 h = (bf16)f;
    return __builtin_bit_cast(uint16_t, h);
}
static __device__ __forceinline__ uint32_t pack_bf16(float lo, float hi) {
    return (uint32_t)bfbits(lo) | ((uint32_t)bfbits(hi) << 16);
}
// raw v_exp_f32: no libm range wrapper.  exp2(-1e30) == +0 in HW.
static __device__ __forceinline__ float fexp2(float x) {
#if __has_builtin(__builtin_amdgcn_exp2f)
    return __builtin_amdgcn_exp2f(x);
#else
    float r; asm("v_exp_f32 %0, %1" : "=v"(r) : "v"(x)); return r;
#endif
}
// async global->LDS DMA, 16B per lane.
static __device__ __forceinline__ void gld_lds16(const void* g, void* l) {
    __builtin_amdgcn_global_load_lds(
        (const __attribute__((address_space(1))) void*)g,
        (__attribute__((address_space(3))) void*)l, 16, 0, 0);
}

// ---------------------------------------------------------------------------
// Kernel 0: one-shot fp32 -> bf16 conversion of hs and all weights.
// ---------------------------------------------------------------------------
__global__ __launch_bounds__(256) void to_bf16(
    const float* __restrict__ hs, const float* __restrict__ Wq,
    const float* __restrict__ Wk, const float* __restrict__ Wv,
    const float* __restrict__ Wo,
    bf16* __restrict__ hsb, bf16* __restrict__ Wb, bf16* __restrict__ Wob)
{
    size_t idx = ((size_t)blockIdx.x * 256 + threadIdx.x) * 8;
    const float* src; bf16* dst; size_t off;
    if (idx < 2097152)      { src = hs; dst = hsb;        off = idx; }
    else if (idx < 2162688) { src = Wq; dst = Wb;         off = idx - 2097152; }
    else if (idx < 2195456) { src = Wk; dst = Wb + 65536; off = idx - 2162688; }
    else if (idx < 2228224) { src = Wv; dst = Wb + 98304; off = idx - 2195456; }
    else                    { src = Wo; dst = Wob;        off = idx - 2228224; }
    float4 a = *(const float4*)&src[off];
    float4 b = *(const float4*)&src[off + 4];
    uint32_t u0 = pack_bf16(a.x, a.y);
    uint32_t u1 = pack_bf16(a.z, a.w);
    uint32_t u2 = pack_bf16(b.x, b.y);
    uint32_t u3 = pack_bf16(b.z, b.w);
    *(uint4*)&dst[off] = make_uint4(u0, u1, u2, u3);
}

// ---------------------------------------------------------------------------
// Kernel 1: QKV projection + RoPE -- single-shot DMA-staged bf16 GEMM.
// ---------------------------------------------------------------------------
__global__ __launch_bounds__(256, 2) void qkv2(
    const bf16* __restrict__ hsb, const bf16* __restrict__ Wb,
    bf16* __restrict__ qws, bf16* __restrict__ kws, bf16* __restrict__ vtws)
{
    __shared__ bf16 As[64 * 256];   // 32 KB linear, rows 512 B
    __shared__ bf16 Bs[64 * 256];
    const int t = threadIdx.x;
    const int wid = t >> 6, lane = t & 63;
    const int g = lane >> 4, c = lane & 15;
    const int n0 = blockIdx.x * 64;
    const int m0 = blockIdx.y * 64;

    {
        const int half = lane >> 5;
        const int seg = lane & 31;
        #pragma unroll
        for (int i = 0; i < 8; ++i) {
            const int row = (i * 4 + wid) * 2 + half;
            const int sseg = seg ^ (row & 7);
            gld_lds16(hsb + (size_t)(m0 + row) * 256 + sseg * 8,
                      (char*)As + wid * 1024 + i * 4096);
            gld_lds16(Wb + (size_t)(n0 + row) * 256 + sseg * 8,
                      (char*)Bs + wid * 1024 + i * 4096);
        }
    }
    __syncthreads();

    const f32x4 zf = {0.f, 0.f, 0.f, 0.f};
    f32x4 acc[4] = {zf, zf, zf, zf};
    const int r = wid * 16 + c;
    const int aBase = r * 512;
    const int s7 = c & 7;
    #pragma unroll
    for (int j = 0; j < 8; ++j) {
        const int so = ((4 * j + g) ^ s7) << 4;
        bf16x8 af = *(const bf16x8*)((const char*)As + aBase + so);
        #pragma unroll
        for (int nt = 0; nt < 4; ++nt) {
            bf16x8 bfr = *(const bf16x8*)((const char*)Bs + (nt * 16 + c) * 512 + so);
            acc[nt] = __builtin_amdgcn_mfma_f32_16x16x32_bf16(af, bfr, acc[nt], 0, 0, 0);
        }
    }

    const float qscale = 1.4426950408889634f * 0.17677669529663687f; // log2e/sqrt(32)
    const float invf = exp2f(-0.83048202372184f * (float)c);          // 10000^(-c/16)
    #pragma unroll
    for (int rr = 0; rr < 4; ++rr) {
        int m = m0 + wid * 16 + g * 4 + rr;
        int b = m >> 12, s = m & (SEQ - 1);
        float sn, cs;
        sincosf((float)s * invf, &sn, &cs);
        if (n0 < 256) {
            #pragma unroll
            for (int np = 0; np < 4; np += 2) {
                int h = (n0 + np * 16) >> 5;
                float x1 = acc[np][rr], x2 = acc[np + 1][rr];
                float y1 = (x1 * cs - x2 * sn) * qscale;
                float y2 = (x2 * cs + x1 * sn) * qscale;
                size_t base = ((size_t)(b * NHEAD + h) * SEQ + s) * HDIM;
                qws[base + c] = (bf16)y1;
                qws[base + 16 + c] = (bf16)y2;
            }
        } else if (n0 < 384) {
            #pragma unroll
            for (int np = 0; np < 4; np += 2) {
                int kh = (n0 - 256 + np * 16) >> 5;
                float x1 = acc[np][rr], x2 = acc[np + 1][rr];
                float y1 = x1 * cs - x2 * sn;
                float y2 = x2 * cs + x1 * sn;
                size_t base = ((size_t)(b * NKVH + kh) * SEQ + s) * HDIM;
                kws[base + c] = (bf16)y1;
                kws[base + 16 + c] = (bf16)y2;
            }
        } else {
            #pragma unroll
            for (int nt = 0; nt < 4; ++nt) {
                int ng = n0 + nt * 16 + c - 384;
                int vh = ng >> 5, d = ng & 31;
                vtws[((size_t)(b * NKVH + vh) * HDIM + d) * SEQ + s] = (bf16)acc[nt][rr];
            }
        }
    }
}

// ---------------------------------------------------------------------------
// Kernel 2: causal flash attention, 2-way cross-block K-split, RING-4 LDS
// (two 64-key chunks per barrier), async global_load_lds.
// ---------------------------------------------------------------------------
#define ATT_CHUNK(CI, KBUF, VBUF)                                              \
  do {                                                                         \
    const char* kbuf = (KBUF);                                                 \
    const char* vbuf = (VBUF);                                                 \
    bf16x8 kf0 = *(const bf16x8*)(kbuf + kro);                                 \
    bf16x8 kf1 = *(const bf16x8*)(kbuf + kro + 256);                           \
    bf16x8 kf2 = *(const bf16x8*)(kbuf + kro + 2048);                          \
    bf16x8 kf3 = *(const bf16x8*)(kbuf + kro + 2304);                          \
    bf16x8 vf00 = *(const bf16x8*)(vbuf + vro0 + ((g ^ cx) << 4));             \
    bf16x8 vf01 = *(const bf16x8*)(vbuf + vro1 + ((g ^ cx) << 4));             \
    bf16x8 vf10 = *(const bf16x8*)(vbuf + vro0 + (((4 + g) ^ cx) << 4));       \
    bf16x8 vf11 = *(const bf16x8*)(vbuf + vro1 + (((4 + g) ^ cx) << 4));       \
    const bool diag = ((CI) == d_w);                                           \
    const int qbase = (w & 1) * 32 + c;                                        \
    {                                                                          \
        f32x4 st0 = __builtin_amdgcn_mfma_f32_16x16x32_bf16(kf0, qf0, zf, 0, 0, 0); \
        f32x4 st1 = __builtin_amdgcn_mfma_f32_16x16x32_bf16(kf1, qf0, zf, 0, 0, 0); \
        f32x4 st2 = __builtin_amdgcn_mfma_f32_16x16x32_bf16(kf2, qf0, zf, 0, 0, 0); \
        f32x4 st3 = __builtin_amdgcn_mfma_f32_16x16x32_bf16(kf3, qf0, zf, 0, 0, 0); \
        if (diag) {                                                            \
            const int qoff = qbase;                                            \
            _Pragma("unroll")                                                  \
            for (int rr = 0; rr < 4; ++rr) {                                   \
                if (8 * g + rr > qoff)          st0[rr] = -1e30f;              \
                if (8 * g + 4 + rr > qoff)      st1[rr] = -1e30f;              \
                if (32 + 8 * g + rr > qoff)     st2[rr] = -1e30f;              \
                if (32 + 8 * g + 4 + rr > qoff) st3[rr] = -1e30f;              \
            }                                                                  \
        }                                                                      \
        float p00 = fexp2(st0[0]), p01 = fexp2(st0[1]), p02 = fexp2(st0[2]), p03 = fexp2(st0[3]); \
        float p10 = fexp2(st1[0]), p11 = fexp2(st1[1]), p12 = fexp2(st1[2]), p13 = fexp2(st1[3]); \
        float p20 = fexp2(st2[0]), p21 = fexp2(st2[1]), p22 = fexp2(st2[2]), p23 = fexp2(st2[3]); \
        float p30 = fexp2(st3[0]), p31 = fexp2(st3[1]), p32 = fexp2(st3[2]), p33 = fexp2(st3[3]); \
        union { uint32_t u[4]; bf16x8 v; } pb0, pb1;                           \
        asm("v_cvt_pk_bf16_f32 %0, %1, %2" : "=v"(pb0.u[0]) : "v"(p00), "v"(p01)); \
        asm("v_cvt_pk_bf16_f32 %0, %1, %2" : "=v"(pb0.u[1]) : "v"(p02), "v"(p03)); \
        asm("v_cvt_pk_bf16_f32 %0, %1, %2" : "=v"(pb0.u[2]) : "v"(p10), "v"(p11)); \
        asm("v_cvt_pk_bf16_f32 %0, %1, %2" : "=v"(pb0.u[3]) : "v"(p12), "v"(p13)); \
        asm("v_cvt_pk_bf16_f32 %0, %1, %2" : "=v"(pb1.u[0]) : "v"(p20), "v"(p21)); \
        asm("v_cvt_pk_bf16_f32 %0, %1, %2" : "=v"(pb1.u[1]) : "v"(p22), "v"(p23)); \
        asm("v_cvt_pk_bf16_f32 %0, %1, %2" : "=v"(pb1.u[2]) : "v"(p30), "v"(p31)); \
        asm("v_cvt_pk_bf16_f32 %0, %1, %2" : "=v"(pb1.u[3]) : "v"(p32), "v"(p33)); \
        o00 = __builtin_amdgcn_mfma_f32_16x16x32_bf16(vf00, pb0.v, o00, 0, 0, 0); \
        o01 = __builtin_amdgcn_mfma_f32_16x16x32_bf16(vf01, pb0.v, o01, 0, 0, 0); \
        ol0 = __builtin_amdgcn_mfma_f32_16x16x32_bf16(onesf.v, pb0.v, ol0, 0, 0, 0); \
        o00 = __builtin_amdgcn_mfma_f32_16x16x32_bf16(vf10, pb1.v, o00, 0, 0, 0); \
        o01 = __builtin_amdgcn_mfma_f32_16x16x32_bf16(vf11, pb1.v, o01, 0, 0, 0); \
        ol0 = __builtin_amdgcn_mfma_f32_16x16x32_bf16(onesf.v, pb1.v, ol0, 0, 0, 0); \
    }                                                                          \
    {                                                                          \
        f32x4 st0 = __builtin_amdgcn_mfma_f32_16x16x32_bf16(kf0, qf1, zf, 0, 0, 0); \
        f32x4 st1 = __builtin_amdgcn_mfma_f32_16x16x32_bf16(kf1, qf1, zf, 0, 0, 0); \
        f32x4 st2 = __builtin_amdgcn_mfma_f32_16x16x32_bf16(kf2, qf1, zf, 0, 0, 0); \
        f32x4 st3 = __builtin_amdgcn_mfma_f32_16x16x32_bf16(kf3, qf1, zf, 0, 0, 0); \
        if (diag) {                                                            \
            const int qoff = qbase + 16;                                       \
            _Pragma("unroll")                                                  \
            for (int rr = 0; rr < 4; ++rr) {                                   \
                if (8 * g + rr > qoff)          st0[rr] = -1e30f;              \
                if (8 * g + 4 + rr > qoff)      st1[rr] = -1e30f;              \
                if (32 + 8 * g + rr > qoff)     st2[rr] = -1e30f;              \
                if (32 + 8 * g + 4 + rr > qoff) st3[rr] = -1e30f;              \
            }                                                                  \
        }                                                                      \
        float p00 = fexp2(st0[0]), p01 = fexp2(st0[1]), p02 = fexp2(st0[2]), p03 = fexp2(st0[3]); \
        float p10 = fexp2(st1[0]), p11 = fexp2(st1[1]), p12 = fexp2(st1[2]), p13 = fexp2(st1[3]); \
        float p20 = fexp2(st2[0]), p21 = fexp2(st2[1]), p22 = fexp2(st2[2]), p23 = fexp2(st2[3]); \
        float p30 = fexp2(st3[0]), p31 = fexp2(st3[1]), p32 = fexp2(st3[2]), p33 = fexp2(st3[3]); \
        union { uint32_t u[4]; bf16x8 v; } pb0, pb1;                           \
        asm("v_cvt_pk_bf16_f32 %0, %1, %2" : "=v"(pb0.u[0]) : "v"(p00), "v"(p01)); \
        asm("v_cvt_pk_bf16_f32 %0, %1, %2" : "=v"(pb0.u[1]) : "v"(p02), "v"(p03)); \
        asm("v_cvt_pk_bf16_f32 %0, %1, %2" : "=v"(pb0.u[2]) : "v"(p10), "v"(p11)); \
        asm("v_cvt_pk_bf16_f32 %0, %1, %2" : "=v"(pb0.u[3]) : "v"(p12), "v"(p13)); \
        asm("v_cvt_pk_bf16_f32 %0, %1, %2" : "=v"(pb1.u[0]) : "v"(p20), "v"(p21)); \
        asm("v_cvt_pk_bf16_f32 %0, %1, %2" : "=v"(pb1.u[1]) : "v"(p22), "v"(p23)); \
        asm("v_cvt_pk_bf16_f32 %0, %1, %2" : "=v"(pb1.u[2]) : "v"(p30), "v"(p31)); \
        asm("v_cvt_pk_bf16_f32 %0, %1, %2" : "=v"(pb1.u[3]) : "v"(p32), "v"(p33)); \
        o10 = __builtin_amdgcn_mfma_f32_16x16x32_bf16(vf00, pb0.v, o10, 0, 0, 0); \
        o11 = __builtin_amdgcn_mfma_f32_16x16x32_bf16(vf01, pb0.v, o11, 0, 0, 0); \
        ol1 = __builtin_amdgcn_mfma_f32_16x16x32_bf16(onesf.v, pb0.v, ol1, 0, 0, 0); \
        o10 = __builtin_amdgcn_mfma_f32_16x16x32_bf16(vf10, pb1.v, o10, 0, 0, 0); \
        o11 = __builtin_amdgcn_mfma_f32_16x16x32_bf16(vf11, pb1.v, o11, 0, 0, 0); \
        ol1 = __builtin_amdgcn_mfma_f32_16x16x32_bf16(onesf.v, pb1.v, ol1, 0, 0, 0); \
    }                                                                          \
  } while (0)

__global__ __launch_bounds__(256, 4) void attn_fwd(
    const bf16* __restrict__ qws, const bf16* __restrict__ kws,
    const bf16* __restrict__ vtws,
    float* __restrict__ Oa, float* __restrict__ Ob,
    float* __restrict__ la, float* __restrict__ lb)
{
    __shared__ char smem[32768];        // K ring 4x4KB @0, V ring 4x4KB @16384
    const int t = threadIdx.x;
    const int w = t >> 6, lane = t & 63;
    const int g = lane >> 4, c = lane & 15;
    const int wg = blockIdx.x;
    const int h = wg & 7;                    // XCD pin
    const int rest = wg >> 3;                // 0..127
    const int half = rest & 1;
    const int r2 = rest >> 1;                // 0..63
    const int b = r2 & 1;
    const int T = 31 - (r2 >> 1);            // descending: longest first
    const int kvh = h >> 1;
    const bf16* Kg = kws + (size_t)(b * NKVH + kvh) * SEQ * HDIM;
    const bf16* Vg = vtws + (size_t)(b * NKVH + kvh) * HDIM * SEQ;
    const int cbase = half * (T + 1);        // first chunk
    const int nloc = T + 1;                  // chunks this block
    const int q0 = T * 128 + w * 32;         // wave's first query
    const int d_w = 2 * T + (w >> 1);        // wave's diagonal chunk (global)

    const bf16* Qb = qws + (size_t)(b * NHEAD + h) * SEQ * HDIM;
    bf16x8 qf0 = *(const bf16x8*)&Qb[(size_t)(q0 + c) * HDIM + g * 8];
    bf16x8 qf1 = *(const bf16x8*)&Qb[(size_t)(q0 + 16 + c) * HDIM + g * 8];

    const int sd = t >> 3, sseg = t & 7;
    const bf16* kg_t = Kg + t * 8;                                    // + ch*2048
    const bf16* vg_t = Vg + (size_t)sd * SEQ + (sseg ^ (sd & 7)) * 8; // + ch*64
    char* kl = smem + w * 1024;              // + slot*4096
    char* vl = smem + 16384 + w * 1024;      // + slot*4096

    const int kperm = 8 * (c >> 2) + (c & 3);
    const int kro = kperm * 64 + g * 16;
    const int cx = c & 7;
    const int vro0 = c * 128, vro1 = (16 + c) * 128;

    const f32x4 zf = {0.f, 0.f, 0.f, 0.f};
    union { uint32_t u[4]; bf16x8 v; } onesf;
    onesf.u[0] = onesf.u[1] = onesf.u[2] = onesf.u[3] = 0x3F803F80u;

    f32x4 o00 = zf, o01 = zf, ol0 = zf;
    f32x4 o10 = zf, o11 = zf, ol1 = zf;

    // prologue: stage chunks 0 and 1 into slots 0,1
    gld_lds16(kg_t + (size_t)cbase * 2048, kl);
    gld_lds16(vg_t + (size_t)cbase * 64, vl);
    if (1 < nloc) {
        gld_lds16(kg_t + (size_t)(cbase + 1) * 2048, kl + 4096);
        gld_lds16(vg_t + (size_t)(cbase + 1) * 64, vl + 4096);
    }
    __syncthreads();

    const int nit = (nloc + 1) >> 1;
    #pragma unroll 1
    for (int it = 0; it < nit; ++it) {
        const int s0 = 2 * it, s1 = s0 + 1;
        if (s0 + 2 < nloc) {
            gld_lds16(kg_t + (size_t)(cbase + s0 + 2) * 2048, kl + ((s0 + 2) & 3) * 4096);
            gld_lds16(vg_t + (size_t)(cbase + s0 + 2) * 64, vl + ((s0 + 2) & 3) * 4096);
        }
        if (s1 + 2 < nloc) {
            gld_lds16(kg_t + (size_t)(cbase + s1 + 2) * 2048, kl + ((s1 + 2) & 3) * 4096);
            gld_lds16(vg_t + (size_t)(cbase + s1 + 2) * 64, vl + ((s1 + 2) & 3) * 4096);
        }
        const int ci0 = cbase + s0;
        if (ci0 <= d_w) {
            ATT_CHUNK(ci0, smem + (s0 & 3) * 4096 + 0,
                           smem + 16384 + (s0 & 3) * 4096);
        }
        const int ci1 = cbase + s1;
        if (s1 < nloc && ci1 <= d_w) {
            ATT_CHUNK(ci1, smem + (s1 & 3) * 4096 + 0,
                           smem + 16384 + (s1 & 3) * 4096);
        }
        __syncthreads();
    }

    // epilogue: un-normalized f32 partials; tr overlays dead K region
    float* tr = (float*)(smem + w * 2112);
    float* Op = half ? Ob : Oa;
    float* lp = half ? lb : la;
    #pragma unroll 1
    for (int j = 0; j < 2; ++j) {
        f32x4 a0 = j ? o10 : o00;
        f32x4 a1 = j ? o11 : o01;
        f32x4 al = j ? ol1 : ol0;
        #pragma unroll
        for (int rr = 0; rr < 4; ++rr) {
            tr[c * 33 + 4 * g + rr]      = a0[rr];
            tr[c * 33 + 16 + 4 * g + rr] = a1[rr];
        }
        if (g == 0) lp[((size_t)b * SEQ + q0 + j * 16 + c) * 8 + h] = al[0];
        int q = lane >> 2, dp = (lane & 3) * 8;
        size_t m = (size_t)b * SEQ + q0 + j * 16 + q;
        float4 f0 = make_float4(tr[q * 33 + dp + 0], tr[q * 33 + dp + 1],
                                tr[q * 33 + dp + 2], tr[q * 33 + dp + 3]);
        float4 f1 = make_float4(tr[q * 33 + dp + 4], tr[q * 33 + dp + 5],
                                tr[q * 33 + dp + 6], tr[q * 33 + dp + 7]);
        *(float4*)&Op[m * HID + h * HDIM + dp]     = f0;
        *(float4*)&Op[m * HID + h * HDIM + dp + 4] = f1;
    }
}

// ---------------------------------------------------------------------------
// Kernel 2b: combine K-split partials once: att = (Oa+Ob)/(la+lb), bf16.
// ---------------------------------------------------------------------------
__global__ __launch_bounds__(256) void combine(
    const float* __restrict__ Oa, const float* __restrict__ Ob,
    const float* __restrict__ la, const float* __restrict__ lb,
    bf16* __restrict__ att)
{
    const size_t e = ((size_t)blockIdx.x * 256 + threadIdx.x) * 8;
    const size_t m = e >> 8;
    const int hh = (int)(e & 255) >> 5;
    const float inv = 1.0f / (la[m * 8 + hh] + lb[m * 8 + hh]);
    float4 a0 = *(const float4*)&Oa[e];
    float4 a1 = *(const float4*)&Oa[e + 4];
    float4 b0 = *(const float4*)&Ob[e];
    float4 b1 = *(const float4*)&Ob[e + 4];
    uint32_t u0 = pack_bf16((a0.x + b0.x) * inv, (a0.y + b0.y) * inv);
    uint32_t u1 = pack_bf16((a0.z + b0.z) * inv, (a0.w + b0.w) * inv);
    uint32_t u2 = pack_bf16((a1.x + b1.x) * inv, (a1.y + b1.y) * inv);
    uint32_t u3 = pack_bf16((a1.z + b1.z) * inv, (a1.w + b1.w) * inv);
    *(uint4*)&att[e] = make_uint4(u0, u1, u2, u3);
}

// ---------------------------------------------------------------------------
// Kernel 3: output projection -- single-shot DMA-staged bf16 GEMM.
// ---------------------------------------------------------------------------
__global__ __launch_bounds__(256, 2) void out_proj2(
    const bf16* __restrict__ att, const bf16* __restrict__ Wob,
    float* __restrict__ out)
{
    __shared__ bf16 As[64 * 256];
    __shared__ bf16 Bs[64 * 256];
    const int t = threadIdx.x;
    const int wid = t >> 6, lane = t & 63;
    const int g = lane >> 4, c = lane & 15;
    const int n0 = blockIdx.x * 64;
    const int m0 = blockIdx.y * 64;

    {
        const int half = lane >> 5;
        const int seg = lane & 31;
        #pragma unroll
        for (int i = 0; i < 8; ++i) {
            const int row = (i * 4 + wid) * 2 + half;
            const int sseg = seg ^ (row & 7);
            gld_lds16(att + (size_t)(m0 + row) * 256 + sseg * 8,
                      (char*)As + wid * 1024 + i * 4096);
            gld_lds16(Wob + (size_t)(n0 + row) * 256 + sseg * 8,
                      (char*)Bs + wid * 1024 + i * 4096);
        }
    }
    __syncthreads();

    const f32x4 zf = {0.f, 0.f, 0.f, 0.f};
    f32x4 acc[4] = {zf, zf, zf, zf};
    const int r = wid * 16 + c;
    const int aBase = r * 512;
    const int s7 = c & 7;
    #pragma unroll
    for (int j = 0; j < 8; ++j) {
        const int so = ((4 * j + g) ^ s7) << 4;
        bf16x8 af = *(const bf16x8*)((const char*)As + aBase + so);
        #pragma unroll
        for (int nt = 0; nt < 4; ++nt) {
            bf16x8 bfr = *(const bf16x8*)((const char*)Bs + (nt * 16 + c) * 512 + so);
            acc[nt] = __builtin_amdgcn_mfma_f32_16x16x32_bf16(af, bfr, acc[nt], 0, 0, 0);
        }
    }

    #pragma unroll
    for (int nt = 0; nt < 4; ++nt) {
        #pragma unroll
        for (int rr = 0; rr < 4; ++rr) {
            int m = m0 + wid * 16 + g * 4 + rr;
            out[(size_t)m * HID + n0 + nt * 16 + c] = acc[nt][rr];
        }
    }
}

extern "C" void kernel_launch(void* const* d_in, const int* in_sizes, int n_in,
                              void* d_out, int out_size, void* d_ws, size_t ws_size,
                              hipStream_t stream) {
    const float* hs = (const float*)d_in[0];
    const float* Wq = (const float*)d_in[1];
    const float* Wk = (const float*)d_in[2];
    const float* Wv = (const float*)d_in[3];
    const float* Wo = (const float*)d_in[4];
    char* ws = (char*)d_ws;
    bf16* qws  = (bf16*)(ws);                 // [2][8][4096][32]   4,194,304 B
    bf16* kws  = (bf16*)(ws + 4194304);       // [2][4][4096][32]   2,097,152 B
    bf16* vtws = (bf16*)(ws + 6291456);       // [2][4][32][4096]   2,097,152 B
    bf16* att  = (bf16*)(ws + 8388608);       // [2][4096][256]     4,194,304 B
    float* Oa  = (float*)(ws + 12582912);     // [8192][256] f32    8,388,608 B
    float* Ob  = (float*)(ws + 20971520);     // [8192][256] f32    8,388,608 B
    float* la  = (float*)(ws + 29360128);     // [8192][8]  f32       262,144 B
    float* lb  = (float*)(ws + 29622272);     // [8192][8]  f32       262,144 B
    bf16* hsb  = (bf16*)(ws + 29884416);      // [8192][256] bf16   4,194,304 B
    bf16* Wb   = (bf16*)(ws + 34078720);      // [512][256]  bf16     262,144 B
    bf16* Wob  = (bf16*)(ws + 34340864);      // [256][256]  bf16     131,072 B

    to_bf16<<<1120, 256, 0, stream>>>(hs, Wq, Wk, Wv, Wo, hsb, Wb, Wob);
    qkv2<<<dim3(8, 128), 256, 0, stream>>>(hsb, Wb, qws, kws, vtws);
    attn_fwd<<<1024, 256, 0, stream>>>(qws, kws, vtws, Oa, Ob, la, lb);
    combine<<<1024, 256, 0, stream>>>(Oa, Ob, la, lb, att);
    out_proj2<<<dim3(4, 128), 256, 0, stream>>>(att, Wob, (float*)d_out);
}